// Round 3
// baseline (4228.448 us; speedup 1.0000x reference)
//
#include <hip/hip_runtime.h>
#include <hip/hip_bf16.h>
#include <stdint.h>

#define LSEQ 197
#define NH   12
#define HD   64
#define CDIM 768
#define KSTR 74   // LDS row stride (u16) for K/V: odd dword count -> conflict-free

typedef __bf16 bf16x8 __attribute__((ext_vector_type(8)));
typedef float  f32x4  __attribute__((ext_vector_type(4)));

__device__ __forceinline__ float bflo(unsigned u) { return __uint_as_float(u << 16); }
__device__ __forceinline__ float bfhi(unsigned u) { return __uint_as_float(u & 0xffff0000u); }
__device__ __forceinline__ float bf2f(unsigned short u) { return __uint_as_float(((unsigned)u) << 16); }
__device__ __forceinline__ unsigned short f2bf(float f) {
  unsigned u = __float_as_uint(f);
  unsigned r = 0x7fffu + ((u >> 16) & 1u);
  return (unsigned short)((u + r) >> 16);
}

__device__ __forceinline__ void gload16(const void* g, void* l) {
  __builtin_amdgcn_global_load_lds(
      (const __attribute__((address_space(1))) unsigned int*)(g),
      (__attribute__((address_space(3))) unsigned int*)(l), 16, 0, 0);
}

// ------------------------------------------------------------ dtype detect
// flag=0: data is packed bf16; flag=1: data is fp32.
// bf16 N(0,1) low-u16 exponent field in [96,140] ~always; fp32 low-u16 is
// random mantissa bits -> ~18% in range. Threshold 512/1024 is >25 sigma.
__global__ void detect_dtype(const unsigned* __restrict__ x, int* __restrict__ flag) {
  __shared__ int cnt;
  if (threadIdx.x == 0) cnt = 0;
  __syncthreads();
  int local = 0;
  for (int i = threadIdx.x; i < 1024; i += 256) {
    const unsigned e = (x[i] >> 7) & 0xFFu;   // low u16's bf16 exponent field
    if (e >= 96u && e <= 140u) local++;
  }
  atomicAdd(&cnt, local);
  __syncthreads();
  if (threadIdx.x == 0) *flag = (cnt > 512) ? 0 : 1;
}

// --------------------------------------------------------- bulk conversion
__global__ void convert_to_bf16(const void* __restrict__ in,
                                unsigned short* __restrict__ outb,
                                const int* __restrict__ flag, long n) {
  const long stride = (long)gridDim.x * blockDim.x;
  long i = (long)blockIdx.x * blockDim.x + threadIdx.x;
  if (*flag) {
    const float* f = (const float*)in;
    for (; i < n; i += stride) outb[i] = f2bf(f[i]);
  } else {
    const unsigned short* s = (const unsigned short*)in;
    for (; i < n; i += stride) outb[i] = s[i];
  }
}

// ------------------------------------------------- small tensors (one kernel)
// packed u16 layout: bq@0 bk@768 bv@1536 bo@2304 rel@3072 c2p@11820 p2c@14172 c2c@16524 (end 16536)
__global__ void convert_small(const void* b0, const void* b1, const void* b2, const void* b3,
                              const void* r, const void* cp, const void* pc, const void* cc,
                              unsigned short* __restrict__ out, const int* __restrict__ flag) {
  const int starts[9] = {0, 768, 1536, 2304, 3072, 11820, 14172, 16524, 16536};
  const void* srcs[8] = {b0, b1, b2, b3, r, cp, pc, cc};
  const bool isf = (*flag != 0);
  for (int i = blockIdx.x * blockDim.x + threadIdx.x; i < 16536;
       i += gridDim.x * blockDim.x) {
    int seg = 0;
    while (i >= starts[seg + 1]) seg++;
    const int off = i - starts[seg];
    out[i] = isf ? f2bf(((const float*)srcs[seg])[off])
                 : ((const unsigned short*)srcs[seg])[off];
  }
}

// ------------------------------------------------- transpose 768x768 + cvt
__global__ void transpose768_cvt(const void* __restrict__ in,
                                 unsigned short* __restrict__ out,
                                 const int* __restrict__ flag) {
  __shared__ unsigned short tile[32][33];
  const bool isf = (*flag != 0);
  const int tx = threadIdx.x & 31;
  const int ty = threadIdx.x >> 5;   // 0..7
  const int bx = blockIdx.x, by = blockIdx.y;
#pragma unroll
  for (int j = 0; j < 32; j += 8) {
    const size_t idx = (size_t)(by * 32 + ty + j) * CDIM + bx * 32 + tx;
    tile[ty + j][tx] = isf ? f2bf(((const float*)in)[idx])
                           : ((const unsigned short*)in)[idx];
  }
  __syncthreads();
#pragma unroll
  for (int j = 0; j < 32; j += 8)
    out[(size_t)(bx * 32 + ty + j) * CDIM + by * 32 + tx] = tile[tx][ty + j];
}

// ------------------------------------------------------------------- GEMM
// C[M][N] = A[M][K] @ Bt[N][K]^T + bias[N]; A,Bt,bias bf16, fp32 accum.
// Output bf16, or fp32 iff (outf32 && *outf32). m97-pedigree structure.
__global__ __launch_bounds__(256, 2) void gemm_bt_bias(
    const unsigned short* __restrict__ A,
    const unsigned short* __restrict__ Bt,
    const unsigned short* __restrict__ bias,
    void* __restrict__ C,
    int M, int N, int K,
    const int* __restrict__ outf32) {
  __shared__ unsigned short As[128 * 32];
  __shared__ unsigned short Bs[128 * 32];

  const int tid  = threadIdx.x;
  const int lane = tid & 63;
  const int wid  = tid >> 6;
  const int bm = blockIdx.y, bn = blockIdx.x;
  const int wm = wid >> 1, wn = wid & 1;
  const bool wf32 = (outf32 != nullptr) && (*outf32 != 0);

  const int srow = (wid * 2) * 16 + (lane >> 2);
  const int scol = (lane & 3) * 8;
  const unsigned short* Ag = A  + (size_t)(bm * 128 + srow) * K + scol;
  const unsigned short* Bg = Bt + (size_t)(bn * 128 + srow) * K + scol;
  unsigned short* lA0 = &As[(wid * 2) * 16 * 32];
  unsigned short* lA1 = lA0 + 16 * 32;
  unsigned short* lB0 = &Bs[(wid * 2) * 16 * 32];
  unsigned short* lB1 = lB0 + 16 * 32;

  f32x4 acc[4][4] = {};

  for (int kt = 0; kt < K; kt += 32) {
    gload16(Ag, lA0);
    gload16(Ag + (size_t)16 * K, lA1);
    gload16(Bg, lB0);
    gload16(Bg + (size_t)16 * K, lB1);
    Ag += 32; Bg += 32;
    __syncthreads();   // drains vmcnt(0) -> LDS tiles valid

    bf16x8 fa[4], fb[4];
#pragma unroll
    for (int t = 0; t < 4; ++t) {
      fa[t] = *(const bf16x8*)&As[(wm * 64 + t * 16 + (lane & 15)) * 32 + (lane >> 4) * 8];
      fb[t] = *(const bf16x8*)&Bs[(wn * 64 + t * 16 + (lane & 15)) * 32 + (lane >> 4) * 8];
    }
#pragma unroll
    for (int mt = 0; mt < 4; ++mt)
#pragma unroll
      for (int nt = 0; nt < 4; ++nt)
        acc[mt][nt] = __builtin_amdgcn_mfma_f32_16x16x32_bf16(fa[mt], fb[nt], acc[mt][nt], 0, 0, 0);
    __syncthreads();   // before next stage overwrites tiles
  }

#pragma unroll
  for (int nt = 0; nt < 4; ++nt) {
    const int col = bn * 128 + wn * 64 + nt * 16 + (lane & 15);
    const float bv = bf2f(bias[col]);
#pragma unroll
    for (int mt = 0; mt < 4; ++mt) {
      const int row0 = bm * 128 + wm * 64 + mt * 16 + (lane >> 4) * 4;
#pragma unroll
      for (int r = 0; r < 4; ++r) {
        const float val = acc[mt][nt][r] + bv;
        const size_t idx = (size_t)(row0 + r) * N + col;
        if (wf32) ((float*)C)[idx] = val;
        else      ((unsigned short*)C)[idx] = f2bf(val);
      }
    }
  }
}

// --------------------------------------------------------------- attention
__device__ __forceinline__ float bias_val(
    const unsigned short* __restrict__ rel,
    const unsigned short* __restrict__ c2p,
    const unsigned short* __restrict__ p2c,
    const unsigned short* __restrict__ c2c,
    int h, int q, int k) {
  if (q == 0) {
    return (k == 0) ? bf2f(c2c[h]) : bf2f(c2p[h * 196 + (k - 1)]);
  }
  if (k == 0) return bf2f(p2c[h * 196 + (q - 1)]);
  const int pi = q - 1, pj = k - 1;
  const int dh = pi / 14 - pj / 14 + 13;
  const int dw = pi % 14 - pj % 14 + 13;
  return bf2f(rel[(dh * 27 + dw) * 12 + h]);
}

__global__ __launch_bounds__(256, 1) void attn_kernel(
    const unsigned short* __restrict__ Q,
    const unsigned short* __restrict__ Kg,
    const unsigned short* __restrict__ Vg,
    const unsigned short* __restrict__ sm,   // converted small-tensor pack
    unsigned short* __restrict__ ctx) {
  __shared__ unsigned short Kh[LSEQ * KSTR];   // 29,156 B
  __shared__ unsigned short Vh[LSEQ * KSTR];   // 29,156 B

  const unsigned short* rel = sm + 3072;
  const unsigned short* c2p = sm + 11820;
  const unsigned short* p2c = sm + 14172;
  const unsigned short* c2c = sm + 16524;

  const int tid  = threadIdx.x;
  const int lane = tid & 63;
  const int wid  = tid >> 6;
  const int bh = blockIdx.x;
  const int b = bh / NH, h = bh % NH;
  const size_t base = ((size_t)b * LSEQ) * CDIM + (size_t)h * HD;

  for (int e2 = tid; e2 < LSEQ * 32; e2 += 256) {
    const int l = e2 >> 5, dp = (e2 & 31) * 2;
    *(unsigned*)&Kh[l * KSTR + dp] = *(const unsigned*)&Kg[base + (size_t)l * CDIM + dp];
    *(unsigned*)&Vh[l * KSTR + dp] = *(const unsigned*)&Vg[base + (size_t)l * CDIM + dp];
  }
  __syncthreads();

  for (int p = wid; p < 99; p += 4) {
    const int r0 = 2 * p;
    const bool dup = (r0 + 1 >= LSEQ);
    const int r1 = dup ? r0 : r0 + 1;

    const float q0r = bf2f(Q[base + (size_t)r0 * CDIM + lane]) * 0.125f;
    const float q1r = bf2f(Q[base + (size_t)r1 * CDIM + lane]) * 0.125f;

    const unsigned short* krow[4];
#pragma unroll
    for (int j = 0; j < 4; ++j) {
      int k = j * 64 + lane;
      krow[j] = &Kh[(k > 196 ? 196 : k) * KSTR];
    }

    float a0[4] = {0.f, 0.f, 0.f, 0.f};
    float a1[4] = {0.f, 0.f, 0.f, 0.f};
#pragma unroll
    for (int d = 0; d < 64; d += 2) {
      const float q00 = __shfl(q0r, d), q01 = __shfl(q0r, d + 1);
      const float q10 = __shfl(q1r, d), q11 = __shfl(q1r, d + 1);
#pragma unroll
      for (int j = 0; j < 4; ++j) {
        const unsigned uu = *(const unsigned*)(krow[j] + d);
        const float k0 = bflo(uu), k1 = bfhi(uu);
        a0[j] += q00 * k0 + q01 * k1;
        a1[j] += q10 * k0 + q11 * k1;
      }
    }

    float s0[4], s1[4];
#pragma unroll
    for (int j = 0; j < 4; ++j) {
      const int k = j * 64 + lane;
      if (k < LSEQ) {
        s0[j] = a0[j] + bias_val(rel, c2p, p2c, c2c, h, r0, k);
        s1[j] = a1[j] + bias_val(rel, c2p, p2c, c2c, h, r1, k);
      } else {
        s0[j] = -1e30f;
        s1[j] = -1e30f;
      }
    }

    float m0 = fmaxf(fmaxf(s0[0], s0[1]), fmaxf(s0[2], s0[3]));
    float m1 = fmaxf(fmaxf(s1[0], s1[1]), fmaxf(s1[2], s1[3]));
#pragma unroll
    for (int o = 32; o > 0; o >>= 1) {
      m0 = fmaxf(m0, __shfl_xor(m0, o));
      m1 = fmaxf(m1, __shfl_xor(m1, o));
    }
    float t0 = 0.f, t1 = 0.f;
#pragma unroll
    for (int j = 0; j < 4; ++j) {
      s0[j] = __expf(s0[j] - m0); t0 += s0[j];
      s1[j] = __expf(s1[j] - m1); t1 += s1[j];
    }
#pragma unroll
    for (int o = 32; o > 0; o >>= 1) {
      t0 += __shfl_xor(t0, o);
      t1 += __shfl_xor(t1, o);
    }
    const float i0 = 1.f / t0, i1 = 1.f / t1;

    float o0 = 0.f, o1 = 0.f;
#pragma unroll
    for (int j = 0; j < 3; ++j) {
#pragma unroll 16
      for (int t = 0; t < 64; ++t) {
        const float p0 = __shfl(s0[j], t);
        const float p1 = __shfl(s1[j], t);
        const float v = bf2f(Vh[(j * 64 + t) * KSTR + lane]);
        o0 += p0 * v; o1 += p1 * v;
      }
    }
#pragma unroll
    for (int t = 0; t < 5; ++t) {
      const float p0 = __shfl(s0[3], t);
      const float p1 = __shfl(s1[3], t);
      const float v = bf2f(Vh[(192 + t) * KSTR + lane]);
      o0 += p0 * v; o1 += p1 * v;
    }
    o0 *= i0; o1 *= i1;

    ctx[base + (size_t)r0 * CDIM + lane] = f2bf(o0);
    if (!dup) ctx[base + (size_t)r1 * CDIM + lane] = f2bf(o1);
  }
}

// ------------------------------------------------------------------ launch
extern "C" void kernel_launch(void* const* d_in, const int* in_sizes, int n_in,
                              void* d_out, int out_size, void* d_ws, size_t ws_size,
                              hipStream_t stream) {
  const void* X   = d_in[0];
  const void* Wq  = d_in[1];
  const void* bq  = d_in[2];
  const void* Wk  = d_in[3];
  const void* bk  = d_in[4];
  const void* Wv  = d_in[5];
  const void* bv  = d_in[6];
  const void* Wo  = d_in[7];
  const void* bo  = d_in[8];
  const void* rel = d_in[9];
  const void* c2p = d_in[10];
  const void* p2c = d_in[11];
  const void* c2c = d_in[12];

  char* ws = (char*)d_ws;
  const size_t FLAG_OFF = 0;
  const size_t SM_OFF   = 256;                       // 16536 u16 -> 33,072 B
  const size_t WT_OFF   = 40960;
  const size_t WT_SZ    = (size_t)CDIM * CDIM * 2;   // 1,179,648 B
  const size_t XB_OFF   = WT_OFF + 4 * WT_SZ;
  const size_t X_SZ     = (size_t)50432 * CDIM * 2;  // 77,463,552 B
  int* flag = (int*)(ws + FLAG_OFF);
  unsigned short* smb = (unsigned short*)(ws + SM_OFF);
  unsigned short* WqT = (unsigned short*)(ws + WT_OFF + 0 * WT_SZ);
  unsigned short* WkT = (unsigned short*)(ws + WT_OFF + 1 * WT_SZ);
  unsigned short* WvT = (unsigned short*)(ws + WT_OFF + 2 * WT_SZ);
  unsigned short* WoT = (unsigned short*)(ws + WT_OFF + 3 * WT_SZ);
  unsigned short* Xb  = (unsigned short*)(ws + XB_OFF + 0 * X_SZ);
  unsigned short* Qb  = (unsigned short*)(ws + XB_OFF + 1 * X_SZ);
  unsigned short* Kb  = (unsigned short*)(ws + XB_OFF + 2 * X_SZ);
  unsigned short* Vb  = (unsigned short*)(ws + XB_OFF + 3 * X_SZ);
  unsigned short* Cb  = (unsigned short*)(ws + XB_OFF + 4 * X_SZ);

  detect_dtype<<<1, 256, 0, stream>>>((const unsigned*)X, flag);

  convert_to_bf16<<<4096, 256, 0, stream>>>(X, Xb, flag, (long)50432 * CDIM);
  convert_small<<<65, 256, 0, stream>>>(bq, bk, bv, bo, rel, c2p, p2c, c2c, smb, flag);

  dim3 tgrid(24, 24);
  transpose768_cvt<<<tgrid, 256, 0, stream>>>(Wq, WqT, flag);
  transpose768_cvt<<<tgrid, 256, 0, stream>>>(Wk, WkT, flag);
  transpose768_cvt<<<tgrid, 256, 0, stream>>>(Wv, WvT, flag);
  transpose768_cvt<<<tgrid, 256, 0, stream>>>(Wo, WoT, flag);

  dim3 ggrid(6, 394);   // N/128 x M/128
  gemm_bt_bias<<<ggrid, 256, 0, stream>>>(Xb, WqT, smb + 0,    Qb, 50432, CDIM, CDIM, nullptr);
  gemm_bt_bias<<<ggrid, 256, 0, stream>>>(Xb, WkT, smb + 768,  Kb, 50432, CDIM, CDIM, nullptr);
  gemm_bt_bias<<<ggrid, 256, 0, stream>>>(Xb, WvT, smb + 1536, Vb, 50432, CDIM, CDIM, nullptr);

  attn_kernel<<<dim3(256 * NH), 256, 0, stream>>>(Qb, Kb, Vb, smb, Cb);

  gemm_bt_bias<<<ggrid, 256, 0, stream>>>(Cb, WoT, smb + 2304, d_out, 50432, CDIM, CDIM, flag);
}

// Round 4
// 897.384 us; speedup vs baseline: 4.7120x; 4.7120x over previous
//
#include <hip/hip_runtime.h>
#include <hip/hip_bf16.h>
#include <stdint.h>

#define LSEQ 197
#define NH   12
#define HD   64
#define CDIM 768

// attention LDS strides (u16 units); all row strides are multiples of 8 u16
// (16 B) so bf16x8 LDS reads are b128-aligned.
#define KSTRD 72    // K rows: 36 dw -> lanes n,n+8 share bank start = 2-way (free)
#define VSTRD 232   // V^T rows: 116 dw -> 2-way
#define PSTRD 40    // P scratch rows: 20 dw -> 2-way

typedef __bf16 bf16x8 __attribute__((ext_vector_type(8)));
typedef float  f32x4  __attribute__((ext_vector_type(4)));

__device__ __forceinline__ float bf2f(unsigned short u) { return __uint_as_float(((unsigned)u) << 16); }
__device__ __forceinline__ unsigned short f2bf(float f) {
  unsigned u = __float_as_uint(f);
  unsigned r = 0x7fffu + ((u >> 16) & 1u);
  return (unsigned short)((u + r) >> 16);
}

__device__ __forceinline__ void gload16(const void* g, void* l) {
  __builtin_amdgcn_global_load_lds(
      (const __attribute__((address_space(1))) unsigned int*)(g),
      (__attribute__((address_space(3))) unsigned int*)(l), 16, 0, 0);
}

// ------------------------------------------------------------ dtype detect
__global__ void detect_dtype(const unsigned* __restrict__ x, int* __restrict__ flag) {
  __shared__ int cnt;
  if (threadIdx.x == 0) cnt = 0;
  __syncthreads();
  int local = 0;
  for (int i = threadIdx.x; i < 1024; i += 256) {
    const unsigned e = (x[i] >> 7) & 0xFFu;
    if (e >= 96u && e <= 140u) local++;
  }
  atomicAdd(&cnt, local);
  __syncthreads();
  if (threadIdx.x == 0) *flag = (cnt > 512) ? 0 : 1;
}

// --------------------------------------------------------- bulk conversion
__global__ void convert_to_bf16(const void* __restrict__ in,
                                unsigned short* __restrict__ outb,
                                const int* __restrict__ flag, long n) {
  const long stride = (long)gridDim.x * blockDim.x;
  long i = (long)blockIdx.x * blockDim.x + threadIdx.x;
  if (*flag) {
    const float* f = (const float*)in;
    for (; i < n; i += stride) outb[i] = f2bf(f[i]);
  } else {
    const unsigned short* s = (const unsigned short*)in;
    for (; i < n; i += stride) outb[i] = s[i];
  }
}

// ------------------------------------------------- small tensors (one kernel)
// packed u16: bq@0 bk@768 bv@1536 bo@2304 rel@3072 c2p@11820 p2c@14172 c2c@16524
__global__ void convert_small(const void* b0, const void* b1, const void* b2, const void* b3,
                              const void* r, const void* cp, const void* pc, const void* cc,
                              unsigned short* __restrict__ out, const int* __restrict__ flag) {
  const int starts[9] = {0, 768, 1536, 2304, 3072, 11820, 14172, 16524, 16536};
  const void* srcs[8] = {b0, b1, b2, b3, r, cp, pc, cc};
  const bool isf = (*flag != 0);
  for (int i = blockIdx.x * blockDim.x + threadIdx.x; i < 16536;
       i += gridDim.x * blockDim.x) {
    int seg = 0;
    while (i >= starts[seg + 1]) seg++;
    const int off = i - starts[seg];
    out[i] = isf ? f2bf(((const float*)srcs[seg])[off])
                 : ((const unsigned short*)srcs[seg])[off];
  }
}

// ---------------------------------------------------- bias matrix precompute
// biasM[h][q][k], q,k padded to 208 (pads = 0).
__global__ void bias_build(const unsigned short* __restrict__ sm,
                           unsigned short* __restrict__ biasM) {
  const unsigned short* rel = sm + 3072;
  const unsigned short* c2p = sm + 11820;
  const unsigned short* p2c = sm + 14172;
  const unsigned short* c2c = sm + 16524;
  const int hq = blockIdx.x;           // h*208 + q
  const int h = hq / 208, q = hq % 208;
  const int k = threadIdx.x;
  if (k >= 208) return;
  unsigned short v = 0;
  if (q < 197 && k < 197) {
    if (q == 0) {
      v = (k == 0) ? c2c[h] : c2p[h * 196 + (k - 1)];
    } else if (k == 0) {
      v = p2c[h * 196 + (q - 1)];
    } else {
      const int pi = q - 1, pj = k - 1;
      const int dh = pi / 14 - pj / 14 + 13;
      const int dw = pi % 14 - pj % 14 + 13;
      v = rel[(dh * 27 + dw) * 12 + h];
    }
  }
  biasM[(size_t)hq * 208 + k] = v;
}

// ------------------------------------------------- transpose 768x768 + cvt
__global__ void transpose768_cvt(const void* __restrict__ in,
                                 unsigned short* __restrict__ out,
                                 const int* __restrict__ flag) {
  __shared__ unsigned short tile[32][33];
  const bool isf = (*flag != 0);
  const int tx = threadIdx.x & 31;
  const int ty = threadIdx.x >> 5;
  const int bx = blockIdx.x, by = blockIdx.y;
#pragma unroll
  for (int j = 0; j < 32; j += 8) {
    const size_t idx = (size_t)(by * 32 + ty + j) * CDIM + bx * 32 + tx;
    tile[ty + j][tx] = isf ? f2bf(((const float*)in)[idx])
                           : ((const unsigned short*)in)[idx];
  }
  __syncthreads();
#pragma unroll
  for (int j = 0; j < 32; j += 8)
    out[(size_t)(bx * 32 + ty + j) * CDIM + by * 32 + tx] = tile[tx][ty + j];
}

// ------------------------------------------------------------------- GEMM
__global__ __launch_bounds__(256, 2) void gemm_bt_bias(
    const unsigned short* __restrict__ A,
    const unsigned short* __restrict__ Bt,
    const unsigned short* __restrict__ bias,
    void* __restrict__ C,
    int M, int N, int K,
    const int* __restrict__ outf32) {
  __shared__ unsigned short As[128 * 32];
  __shared__ unsigned short Bs[128 * 32];

  const int tid  = threadIdx.x;
  const int lane = tid & 63;
  const int wid  = tid >> 6;
  const int bm = blockIdx.y, bn = blockIdx.x;
  const int wm = wid >> 1, wn = wid & 1;
  const bool wf32 = (outf32 != nullptr) && (*outf32 != 0);

  const int srow = (wid * 2) * 16 + (lane >> 2);
  const int scol = (lane & 3) * 8;
  const unsigned short* Ag = A  + (size_t)(bm * 128 + srow) * K + scol;
  const unsigned short* Bg = Bt + (size_t)(bn * 128 + srow) * K + scol;
  unsigned short* lA0 = &As[(wid * 2) * 16 * 32];
  unsigned short* lA1 = lA0 + 16 * 32;
  unsigned short* lB0 = &Bs[(wid * 2) * 16 * 32];
  unsigned short* lB1 = lB0 + 16 * 32;

  f32x4 acc[4][4] = {};

  for (int kt = 0; kt < K; kt += 32) {
    gload16(Ag, lA0);
    gload16(Ag + (size_t)16 * K, lA1);
    gload16(Bg, lB0);
    gload16(Bg + (size_t)16 * K, lB1);
    Ag += 32; Bg += 32;
    __syncthreads();

    bf16x8 fa[4], fb[4];
#pragma unroll
    for (int t = 0; t < 4; ++t) {
      fa[t] = *(const bf16x8*)&As[(wm * 64 + t * 16 + (lane & 15)) * 32 + (lane >> 4) * 8];
      fb[t] = *(const bf16x8*)&Bs[(wn * 64 + t * 16 + (lane & 15)) * 32 + (lane >> 4) * 8];
    }
#pragma unroll
    for (int mt = 0; mt < 4; ++mt)
#pragma unroll
      for (int nt = 0; nt < 4; ++nt)
        acc[mt][nt] = __builtin_amdgcn_mfma_f32_16x16x32_bf16(fa[mt], fb[nt], acc[mt][nt], 0, 0, 0);
    __syncthreads();
  }

#pragma unroll
  for (int nt = 0; nt < 4; ++nt) {
    const int col = bn * 128 + wn * 64 + nt * 16 + (lane & 15);
    const float bv = bf2f(bias[col]);
#pragma unroll
    for (int mt = 0; mt < 4; ++mt) {
      const int row0 = bm * 128 + wm * 64 + mt * 16 + (lane >> 4) * 4;
#pragma unroll
      for (int r = 0; r < 4; ++r) {
        const float val = acc[mt][nt][r] + bv;
        const size_t idx = (size_t)(row0 + r) * N + col;
        if (wf32) ((float*)C)[idx] = val;
        else      ((unsigned short*)C)[idx] = f2bf(val);
      }
    }
  }
}

// ------------------------------------------------------- MFMA attention
// One block per (b,h). 4 waves; wave w handles q-tiles mt = w, w+4, w+8, w+12.
// Full S row (13 f32x4) register-resident -> exact one-pass softmax.
__global__ __launch_bounds__(256, 2) void attn_mfma(
    const unsigned short* __restrict__ Q,
    const unsigned short* __restrict__ Kg,
    const unsigned short* __restrict__ Vg,
    const unsigned short* __restrict__ biasM,
    unsigned short* __restrict__ ctx) {
  __shared__ unsigned short Kh[208 * KSTRD];   // 29,952 B (rows >=197 unread-garbage: masked)
  __shared__ unsigned short Vt[64 * VSTRD];    // 29,696 B (V transposed; k-pad zeroed)
  __shared__ unsigned short Pt[4 * 16 * PSTRD]; // 5,120 B (per-wave P scratch)

  const int tid  = threadIdx.x;
  const int lane = tid & 63;
  const int wid  = tid >> 6;
  const int bh = blockIdx.x;
  const int b = bh / NH, h = bh % NH;
  const size_t base = ((size_t)b * LSEQ) * CDIM + (size_t)h * HD;

  // stage K (row-major) and V^T
  for (int e2 = tid; e2 < LSEQ * 32; e2 += 256) {
    const int l = e2 >> 5, d2 = (e2 & 31) * 2;
    const unsigned kv = *(const unsigned*)&Kg[base + (size_t)l * CDIM + d2];
    const unsigned vv = *(const unsigned*)&Vg[base + (size_t)l * CDIM + d2];
    *(unsigned*)&Kh[l * KSTRD + d2] = kv;
    Vt[d2 * VSTRD + l]       = (unsigned short)(vv & 0xffffu);
    Vt[(d2 + 1) * VSTRD + l] = (unsigned short)(vv >> 16);
  }
  // zero V^T pad cols k=197..223 (read by the last k-frag; 0 * x keeps O exact)
  for (int i = tid; i < 64 * 27; i += 256) {
    const int d = i / 27, c = 197 + i % 27;
    Vt[d * VSTRD + c] = 0;
  }
  __syncthreads();

  unsigned short* pt = &Pt[wid * 16 * PSTRD];
  const int krd = (lane & 15) * KSTRD + (lane >> 4) * 8;  // K B-frag offset
  const int prd = (lane & 15) * PSTRD + (lane >> 4) * 8;  // P A-frag read offset
  const int pwr = (lane >> 4) * 4;                        // P write row base
  const int pwc = lane & 15;                              // P write col

  for (int mt = wid; mt < 13; mt += 4) {
    // Q A-frags (global, 16B aligned; pad rows clamped to 196)
    const int qm = mt * 16 + (lane & 15);
    const unsigned short* qp = &Q[base + (size_t)(qm > 196 ? 196 : qm) * CDIM + (lane >> 4) * 8];
    const bf16x8 qf0 = *(const bf16x8*)qp;
    const bf16x8 qf1 = *(const bf16x8*)(qp + 32);

    // S = Q K^T  (13 n-tiles x 2 MFMAs)
    f32x4 s[13];
#pragma unroll
    for (int nt = 0; nt < 13; ++nt) {
      const bf16x8 kb0 = *(const bf16x8*)&Kh[nt * 16 * KSTRD + krd];
      const bf16x8 kb1 = *(const bf16x8*)&Kh[nt * 16 * KSTRD + krd + 32];
      f32x4 a = {0.f, 0.f, 0.f, 0.f};
      a = __builtin_amdgcn_mfma_f32_16x16x32_bf16(qf0, kb0, a, 0, 0, 0);
      a = __builtin_amdgcn_mfma_f32_16x16x32_bf16(qf1, kb1, a, 0, 0, 0);
      s[nt] = a;
    }

    // scale + bias (precomputed, padded table)
    const unsigned short* bp =
        biasM + ((size_t)h * 208 + mt * 16 + pwr) * 208 + pwc;
#pragma unroll
    for (int nt = 0; nt < 13; ++nt)
#pragma unroll
      for (int r = 0; r < 4; ++r)
        s[nt][r] = s[nt][r] * 0.125f + bf2f(bp[r * 208 + nt * 16]);

    // mask invalid keys (k = 192 + (lane&15) >= 197)
    if ((lane & 15) >= 5) {
      s[12][0] = -1e30f; s[12][1] = -1e30f; s[12][2] = -1e30f; s[12][3] = -1e30f;
    }

    // exact softmax per q-row (reduce across lanes sharing lane>>4)
    float inv[4];
#pragma unroll
    for (int r = 0; r < 4; ++r) {
      float m = s[0][r];
#pragma unroll
      for (int nt = 1; nt < 13; ++nt) m = fmaxf(m, s[nt][r]);
      m = fmaxf(m, __shfl_xor(m, 1));
      m = fmaxf(m, __shfl_xor(m, 2));
      m = fmaxf(m, __shfl_xor(m, 4));
      m = fmaxf(m, __shfl_xor(m, 8));
      float sum = 0.f;
#pragma unroll
      for (int nt = 0; nt < 13; ++nt) { s[nt][r] = __expf(s[nt][r] - m); sum += s[nt][r]; }
      sum += __shfl_xor(sum, 1);
      sum += __shfl_xor(sum, 2);
      sum += __shfl_xor(sum, 4);
      sum += __shfl_xor(sum, 8);
      inv[r] = 1.0f / sum;
    }

    // O = P V  (P -> A-layout via per-wave LDS round-trip)
    f32x4 o[4] = {{0.f,0.f,0.f,0.f},{0.f,0.f,0.f,0.f},{0.f,0.f,0.f,0.f},{0.f,0.f,0.f,0.f}};
#pragma unroll
    for (int t = 0; t < 7; ++t) {
#pragma unroll
      for (int r = 0; r < 4; ++r) {
        pt[(pwr + r) * PSTRD + pwc]      = f2bf(s[2 * t][r]);
        pt[(pwr + r) * PSTRD + pwc + 16] = (2 * t + 1 < 13) ? f2bf(s[2 * t + 1][r])
                                                            : (unsigned short)0;
      }
      __threadfence_block();   // wave-local: ds_writes complete before cross-lane read
      const bf16x8 pa = *(const bf16x8*)&pt[prd];
#pragma unroll
      for (int ot = 0; ot < 4; ++ot) {
        const bf16x8 vb =
            *(const bf16x8*)&Vt[(ot * 16 + (lane & 15)) * VSTRD + t * 32 + (lane >> 4) * 8];
        o[ot] = __builtin_amdgcn_mfma_f32_16x16x32_bf16(pa, vb, o[ot], 0, 0, 0);
      }
      __threadfence_block();   // keep next iter's writes after this read
    }

    // store (normalize by 1/l)
#pragma unroll
    for (int ot = 0; ot < 4; ++ot)
#pragma unroll
      for (int r = 0; r < 4; ++r) {
        const int q = mt * 16 + pwr + r;
        if (q < LSEQ)
          ctx[base + (size_t)q * CDIM + ot * 16 + pwc] = f2bf(o[ot][r] * inv[r]);
      }
  }
}

// ------------------------------------------------------------------ launch
extern "C" void kernel_launch(void* const* d_in, const int* in_sizes, int n_in,
                              void* d_out, int out_size, void* d_ws, size_t ws_size,
                              hipStream_t stream) {
  const void* X   = d_in[0];
  const void* Wq  = d_in[1];
  const void* bq  = d_in[2];
  const void* Wk  = d_in[3];
  const void* bk  = d_in[4];
  const void* Wv  = d_in[5];
  const void* bv  = d_in[6];
  const void* Wo  = d_in[7];
  const void* bo  = d_in[8];
  const void* rel = d_in[9];
  const void* c2p = d_in[10];
  const void* p2c = d_in[11];
  const void* c2c = d_in[12];

  char* ws = (char*)d_ws;
  const size_t FLAG_OFF = 0;
  const size_t SM_OFF   = 256;                       // 16536 u16 = 33,072 B
  const size_t BIAS_OFF = 40960;                     // 12*208*208 u16 = 1,038,336 B
  const size_t WT_OFF   = BIAS_OFF + 1040384;        // aligned
  const size_t WT_SZ    = (size_t)CDIM * CDIM * 2;   // 1,179,648 B
  const size_t XB_OFF   = WT_OFF + 4 * WT_SZ;
  const size_t X_SZ     = (size_t)50432 * CDIM * 2;  // 77,463,552 B
  int* flag = (int*)(ws + FLAG_OFF);
  unsigned short* smb   = (unsigned short*)(ws + SM_OFF);
  unsigned short* biasM = (unsigned short*)(ws + BIAS_OFF);
  unsigned short* WqT = (unsigned short*)(ws + WT_OFF + 0 * WT_SZ);
  unsigned short* WkT = (unsigned short*)(ws + WT_OFF + 1 * WT_SZ);
  unsigned short* WvT = (unsigned short*)(ws + WT_OFF + 2 * WT_SZ);
  unsigned short* WoT = (unsigned short*)(ws + WT_OFF + 3 * WT_SZ);
  unsigned short* Xb  = (unsigned short*)(ws + XB_OFF + 0 * X_SZ);
  unsigned short* Qb  = (unsigned short*)(ws + XB_OFF + 1 * X_SZ);
  unsigned short* Kb  = (unsigned short*)(ws + XB_OFF + 2 * X_SZ);
  unsigned short* Vb  = (unsigned short*)(ws + XB_OFF + 3 * X_SZ);
  unsigned short* Cb  = Xb;   // Xb dead after the QKV GEMMs — reuse for ctx

  detect_dtype<<<1, 256, 0, stream>>>((const unsigned*)X, flag);

  convert_to_bf16<<<4096, 256, 0, stream>>>(X, Xb, flag, (long)50432 * CDIM);
  convert_small<<<65, 256, 0, stream>>>(bq, bk, bv, bo, rel, c2p, p2c, c2c, smb, flag);
  bias_build<<<12 * 208, 256, 0, stream>>>(smb, biasM);

  dim3 tgrid(24, 24);
  transpose768_cvt<<<tgrid, 256, 0, stream>>>(Wq, WqT, flag);
  transpose768_cvt<<<tgrid, 256, 0, stream>>>(Wk, WkT, flag);
  transpose768_cvt<<<tgrid, 256, 0, stream>>>(Wv, WvT, flag);
  transpose768_cvt<<<tgrid, 256, 0, stream>>>(Wo, WoT, flag);

  dim3 ggrid(6, 394);   // N/128 x M/128
  gemm_bt_bias<<<ggrid, 256, 0, stream>>>(Xb, WqT, smb + 0,    Qb, 50432, CDIM, CDIM, nullptr);
  gemm_bt_bias<<<ggrid, 256, 0, stream>>>(Xb, WkT, smb + 768,  Kb, 50432, CDIM, CDIM, nullptr);
  gemm_bt_bias<<<ggrid, 256, 0, stream>>>(Xb, WvT, smb + 1536, Vb, 50432, CDIM, CDIM, nullptr);

  attn_mfma<<<dim3(256 * NH), 256, 0, stream>>>(Qb, Kb, Vb, biasM, Cb);

  gemm_bt_bias<<<ggrid, 256, 0, stream>>>(Cb, WoT, smb + 2304, d_out, 50432, CDIM, CDIM, flag);
}